// Round 2
// baseline (383.041 us; speedup 1.0000x reference)
//
#include <hip/hip_runtime.h>

// KL(N(mu_p, diag(exp(ls_p))) || N(mu_q, diag(exp(ls_q)))), closed form,
// reduced to a single scalar:
//   out = 0.5 * ( S / N_samples - d )
// where S = sum over ALL elements of
//   elem = r + exp(-r) + (m_q - m_p)^2 * exp(-ls_q),  r = ls_q - ls_p
// Shapes: (2, 3, 160, 192, 160) fp32. N_total = 29,491,200 (divisible by 4).
// N_samples = N_total / d = 9,830,400, d = 3.
//
// Memory-bound: 4 arrays * 118 MB = 472 MB read. Delivered BW observed
// pinned at ~3.3 TB/s regardless of per-wave ILP (VGPR 16 vs 36 identical)
// -> not latency/MLP-bound. Remaining suspect: block-level work imbalance
// (grid-stride gave 3-vs-4 chunks per block = +14% makespan) and tail
// occupancy decay. This version: perfectly balanced static contiguous
// split -- 2048 blocks x exactly 3600 float4 each (exact for this shape),
// every CU gets identical bytes, each block streams contiguous 230 KB
// spans per array. Unroll x2 (8 loads in flight). fp64 accumulate, wave
// shuffle reduce, LDS across waves, one double partial per block, then a
// single-block finalize kernel.

#define BLOCKS   2048
#define THREADS  256

__device__ __forceinline__ float kl4(float4 a, float4 b, float4 c, float4 d)
{
    float dx = c.x - a.x, dy = c.y - a.y, dz = c.z - a.z, dw = c.w - a.w;
    float rx = d.x - b.x, ry = d.y - b.y, rz = d.z - b.z, rw = d.w - b.w;
    float e0 = rx + __expf(-rx) + dx * dx * __expf(-d.x);
    float e1 = ry + __expf(-ry) + dy * dy * __expf(-d.y);
    float e2 = rz + __expf(-rz) + dz * dz * __expf(-d.z);
    float e3 = rw + __expf(-rw) + dw * dw * __expf(-d.w);
    return (e0 + e1) + (e2 + e3);
}

__global__ __launch_bounds__(THREADS) void kl_reduce_kernel(
    const float4* __restrict__ mp, const float4* __restrict__ lsp,
    const float4* __restrict__ mq, const float4* __restrict__ lsq,
    double* __restrict__ partials, long n4)
{
    // Perfectly balanced contiguous split: block b owns [start, end).
    // For this shape: n4 = 7,372,800 = 2048 * 3600 exactly (rem = 0).
    const long per   = n4 / BLOCKS;
    const long rem   = n4 % BLOCKS;
    const long b     = blockIdx.x;
    const long start = b * per + (b < rem ? b : rem);
    const long end   = start + per + (b < rem ? 1 : 0);

    double acc = 0.0;
    long i = start + threadIdx.x;

    // Unroll x2: issue all 8 loads before computing. Second element valid
    // iff i + THREADS < end (then i < end too).
    for (; i + THREADS < end; i += 2 * THREADS) {
        const long j = i + THREADS;
        float4 a0 = mp [i], a1 = mp [j];
        float4 b0 = lsp[i], b1 = lsp[j];
        float4 c0 = mq [i], c1 = mq [j];
        float4 d0 = lsq[i], d1 = lsq[j];
        acc += (double)kl4(a0, b0, c0, d0);
        acc += (double)kl4(a1, b1, c1, d1);
    }
    // Tail: at most one more float4 per thread.
    for (; i < end; i += THREADS)
        acc += (double)kl4(mp[i], lsp[i], mq[i], lsq[i]);

    // wave (64-lane) reduction
#pragma unroll
    for (int off = 32; off > 0; off >>= 1)
        acc += __shfl_down(acc, off, 64);

    __shared__ double sdata[THREADS / 64];
    int wave = threadIdx.x >> 6;
    if ((threadIdx.x & 63) == 0) sdata[wave] = acc;
    __syncthreads();

    if (threadIdx.x == 0) {
        double s = 0.0;
#pragma unroll
        for (int w = 0; w < THREADS / 64; ++w) s += sdata[w];
        partials[blockIdx.x] = s;
    }
}

__global__ __launch_bounds__(256) void kl_finalize_kernel(
    const double* __restrict__ partials, int nblocks,
    float* __restrict__ out, double inv_nsamp, double dch)
{
    double acc = 0.0;
    for (int i = threadIdx.x; i < nblocks; i += blockDim.x)
        acc += partials[i];

#pragma unroll
    for (int off = 32; off > 0; off >>= 1)
        acc += __shfl_down(acc, off, 64);

    __shared__ double sdata[4];
    int wave = threadIdx.x >> 6;
    if ((threadIdx.x & 63) == 0) sdata[wave] = acc;
    __syncthreads();

    if (threadIdx.x == 0) {
        double s = 0.0;
#pragma unroll
        for (int w = 0; w < 4; ++w) s += sdata[w];
        out[0] = (float)(0.5 * (s * inv_nsamp - dch));
    }
}

extern "C" void kernel_launch(void* const* d_in, const int* in_sizes, int n_in,
                              void* d_out, int out_size, void* d_ws, size_t ws_size,
                              hipStream_t stream) {
    const float4* mp  = (const float4*)d_in[0];
    const float4* lsp = (const float4*)d_in[1];
    const float4* mq  = (const float4*)d_in[2];
    const float4* lsq = (const float4*)d_in[3];

    long n_total = (long)in_sizes[0];       // 29,491,200
    long n4 = n_total / 4;                  // exactly divisible
    const long d_ch = 3;
    double n_samples = (double)(n_total / d_ch);

    double* partials = (double*)d_ws;       // BLOCKS * 8 bytes = 16 KB

    kl_reduce_kernel<<<BLOCKS, THREADS, 0, stream>>>(mp, lsp, mq, lsq, partials, n4);
    kl_finalize_kernel<<<1, 256, 0, stream>>>(partials, BLOCKS, (float*)d_out,
                                              1.0 / n_samples, (double)d_ch);
}